// Round 1
// baseline (529.862 us; speedup 1.0000x reference)
//
#include <hip/hip_runtime.h>
#include <math.h>

#define NNODES 50000
#define DIM 128
#define HEADS 4
#define DH 32
#define NEG 0.2f

static __device__ __forceinline__ float lrelu(float x) { return x >= 0.f ? x : NEG * x; }

// ---------------- CSR build ----------------
__global__ void k_count(const int* __restrict__ ei, int* __restrict__ deg, int E) {
    int i = blockIdx.x * blockDim.x + threadIdx.x;
    if (i < E) atomicAdd(&deg[ei[E + i]], 1);
}

__global__ __launch_bounds__(1024) void k_scan_block(const int* __restrict__ deg,
                                                     int* __restrict__ rp1,
                                                     int* __restrict__ part, int N) {
    __shared__ int s[1024];
    int n = blockIdx.x * 1024 + threadIdx.x;
    int v = (n < N) ? (deg[n] + 1) : 0;   // +1 self-loop
    s[threadIdx.x] = v;
    __syncthreads();
    for (int off = 1; off < 1024; off <<= 1) {
        int t = 0;
        if (threadIdx.x >= off) t = s[threadIdx.x - off];
        __syncthreads();
        if (threadIdx.x >= off) s[threadIdx.x] += t;
        __syncthreads();
    }
    if (n < N) rp1[n + 1] = s[threadIdx.x];          // inclusive, pre-offset
    if (threadIdx.x == 1023) part[blockIdx.x] = s[1023];
}

__global__ void k_scan_part(const int* __restrict__ part, int* __restrict__ partoff, int nb) {
    int lane = threadIdx.x;
    int v = (lane < nb) ? part[lane] : 0;
    int orig = v;
    for (int off = 1; off < 64; off <<= 1) {
        int t = __shfl_up(v, off);
        if (lane >= off) v += t;
    }
    if (lane < nb) partoff[lane] = v - orig;          // exclusive
}

__global__ void k_scan_add(int* __restrict__ rp, int* __restrict__ cur, int* __restrict__ col,
                           const int* __restrict__ deg, const int* __restrict__ partoff, int N) {
    int n = blockIdx.x * blockDim.x + threadIdx.x;
    if (n >= N) return;
    int v = rp[n + 1] + partoff[n >> 10];
    rp[n + 1] = v;
    cur[n] = v - (deg[n] + 1);     // row start
    col[v - 1] = n;                // self-loop in last slot of the row
    if (n == 0) rp[0] = 0;
}

__global__ void k_scatter(const int* __restrict__ ei, int* __restrict__ cur,
                          int* __restrict__ col, int E) {
    int i = blockIdx.x * blockDim.x + threadIdx.x;
    if (i < E) {
        int s = ei[i], d = ei[E + i];
        int p = atomicAdd(&cur[d], 1);
        col[p] = s;
    }
}

// ---------------- layer 0 shortcut ----------------
// h0 rows identical => z identical per node, softmax collapses to 1/deg,
// out[n] = z0 * (1 + deg(n)); h1 = elu(out) + emb
__global__ void k_z0(const float* __restrict__ emb, const float* __restrict__ W0,
                     float* __restrict__ z0) {
    int c = threadIdx.x;  // 128 threads
    float s = 0.f;
    for (int k = 0; k < DIM; k++) s += emb[k] * W0[k * DIM + c];
    z0[c] = s;
}

__global__ void k_hinit(const float* __restrict__ emb, const float* __restrict__ z0,
                        const int* __restrict__ rp, float* __restrict__ h, int N) {
    int idx = blockIdx.x * blockDim.x + threadIdx.x;
    if (idx >= N * DIM) return;
    int n = idx >> 7, c = idx & 127;
    float degt = (float)(rp[n + 1] - rp[n]);   // includes self-loop
    float o = z0[c] * (1.f + degt);
    float e = o > 0.f ? o : (__expf(o) - 1.f);
    h[idx] = e + emb[c];
}

// ---------------- SGEMM z = h @ W  (+ per-head attention dots) ----------------
#define BM 64
#define BN 64
#define BK 32

__global__ __launch_bounds__(256) void k_gemm(const float* __restrict__ h,
                                              const float* __restrict__ W,
                                              const float* __restrict__ att_s,
                                              const float* __restrict__ att_d,
                                              float* __restrict__ z,
                                              float* __restrict__ a_s,
                                              float* __restrict__ a_d, int N) {
    __shared__ float As[BK][BM + 4];   // A^T: [k][m]
    __shared__ float Bs[BK][BN + 4];
    __shared__ float Ps[BM][17];
    __shared__ float Pd[BM][17];
    int tid = threadIdx.x;
    int tx = tid & 15, ty = tid >> 4;
    int row0 = blockIdx.x * BM, col0 = blockIdx.y * BN;
    float acc[4][4] = {};
    for (int kb = 0; kb < DIM; kb += BK) {
        #pragma unroll
        for (int i = 0; i < 2; i++) {
            int idx = tid * 2 + i;
            int r = idx >> 3, q = idx & 7;
            float4 v = make_float4(0.f, 0.f, 0.f, 0.f);
            int gr = row0 + r;
            if (gr < N) v = *(const float4*)&h[gr * DIM + kb + 4 * q];
            As[4 * q + 0][r] = v.x;
            As[4 * q + 1][r] = v.y;
            As[4 * q + 2][r] = v.z;
            As[4 * q + 3][r] = v.w;
        }
        #pragma unroll
        for (int i = 0; i < 2; i++) {
            int idx = tid * 2 + i;
            int k = idx >> 4, c4 = idx & 15;
            float4 v = *(const float4*)&W[(kb + k) * DIM + col0 + 4 * c4];
            *(float4*)&Bs[k][4 * c4] = v;
        }
        __syncthreads();
        #pragma unroll
        for (int k = 0; k < BK; k++) {
            const float4 a = *(const float4*)&As[k][4 * ty];
            const float4 b = *(const float4*)&Bs[k][4 * tx];
            float av[4] = {a.x, a.y, a.z, a.w};
            float bv[4] = {b.x, b.y, b.z, b.w};
            #pragma unroll
            for (int i = 0; i < 4; i++)
                #pragma unroll
                for (int j = 0; j < 4; j++) acc[i][j] += av[i] * bv[j];
        }
        __syncthreads();
    }
    // epilogue: store z, compute per-head attention partials
    int hh = (col0 + 4 * tx) >> 5;   // global head for this thread's 4 cols
    float asv[4], adv[4];
    #pragma unroll
    for (int j = 0; j < 4; j++) {
        int cm = (4 * tx + j) & 31;
        asv[j] = att_s[hh * DH + cm];
        adv[j] = att_d[hh * DH + cm];
    }
    #pragma unroll
    for (int i = 0; i < 4; i++) {
        float ps = 0.f, pd = 0.f;
        #pragma unroll
        for (int j = 0; j < 4; j++) {
            ps += acc[i][j] * asv[j];
            pd += acc[i][j] * adv[j];
        }
        Ps[4 * ty + i][tx] = ps;
        Pd[4 * ty + i][tx] = pd;
        int gr = row0 + 4 * ty + i;
        if (gr < N)
            *(float4*)&z[gr * DIM + col0 + 4 * tx] =
                make_float4(acc[i][0], acc[i][1], acc[i][2], acc[i][3]);
    }
    __syncthreads();
    // reduce 8 partials per (row, head-in-tile); 2 heads per 64-col tile => no cross-block overlap
    int row = tid & 63, th = (tid >> 6) & 1, sd = tid >> 7;
    const float(*P)[17] = sd ? Pd : Ps;
    float sum = 0.f;
    #pragma unroll
    for (int u = 0; u < 8; u++) sum += P[row][th * 8 + u];
    int gr = row0 + row;
    if (gr < N) {
        int head = blockIdx.y * 2 + th;
        float* dst = sd ? a_d : a_s;
        dst[gr * HEADS + head] = sum;
    }
}

// ---------------- edge aggregation (CSR, softmax fused, elu+residual) ----------------
__global__ __launch_bounds__(128) void k_aggr(const float* __restrict__ z,
                                              const float* __restrict__ a_s,
                                              const float* __restrict__ a_d,
                                              const int* __restrict__ rp,
                                              const int* __restrict__ col,
                                              float* __restrict__ h, int N) {
    int n = blockIdx.x;
    int c = threadIdx.x;          // channel 0..127
    int hh = c >> 5;              // head
    int beg = rp[n], end = rp[n + 1];
    float ad = a_d[n * HEADS + hh];
    // pass 1: per-head max (redundant across the 32 lanes of a head — no reduce needed)
    float amax = -1e30f;
    for (int j = beg; j < end; j++) {
        int s = col[j];
        float a = lrelu(a_s[s * HEADS + hh] + ad);
        amax = fmaxf(amax, a);
    }
    // pass 2: sum exp (den), ex-weighted message, plain message
    float den = 0.f, acc1 = 0.f, acc2 = 0.f;
    for (int j = beg; j < end; j++) {
        int s = col[j];
        float a = lrelu(a_s[s * HEADS + hh] + ad);
        float ex = __expf(a - amax);
        float zv = z[s * DIM + c];
        den += ex;
        acc1 += zv * ex;
        acc2 += zv;
    }
    float out = acc1 / den + acc2;     // sum z*(e/den + 1)
    float e = out > 0.f ? out : (__expf(out) - 1.f);
    h[n * DIM + c] += e;               // residual
}

// ---------------- graph readout + MLP ----------------
__global__ __launch_bounds__(256) void k_readout(const float* __restrict__ h,
                                                 const int* __restrict__ ptr,
                                                 const float* __restrict__ w0,
                                                 const float* __restrict__ b0,
                                                 const float* __restrict__ w1,
                                                 const float* __restrict__ b1,
                                                 float* __restrict__ y, int N) {
    __shared__ float red[256];
    __shared__ float g[DIM];
    int b = blockIdx.x;
    int tid = threadIdx.x;
    // ptr is sorted; binary-search node range of graph b
    int lo = 0, hi = N;
    while (lo < hi) { int m = (lo + hi) >> 1; if (ptr[m] < b) lo = m + 1; else hi = m; }
    int start = lo;
    hi = N;
    while (lo < hi) { int m = (lo + hi) >> 1; if (ptr[m] < b + 1) lo = m + 1; else hi = m; }
    int end = lo;
    int c = tid & 127, part = tid >> 7;
    float acc = 0.f;
    for (int n = start + part; n < end; n += 2) acc += h[n * DIM + c];
    red[tid] = acc;
    __syncthreads();
    if (tid < DIM) {
        float s = red[tid] + red[tid + 128];
        float cnt = (float)(end - start);
        float gv = s / fmaxf(cnt, 1.f);
        g[tid] = fmaxf(gv, 0.f);
    }
    __syncthreads();
    if (tid < 64) {
        float hj = b0[tid];
        for (int k = 0; k < DIM; k++) hj += g[k] * w0[k * 64 + tid];
        hj = fmaxf(hj, 0.f);
        float p = hj * w1[tid];
        #pragma unroll
        for (int off = 32; off > 0; off >>= 1) p += __shfl_down(p, off);
        if (tid == 0) y[b] = p + b1[0];
    }
}

extern "C" void kernel_launch(void* const* d_in, const int* in_sizes, int n_in,
                              void* d_out, int out_size, void* d_ws, size_t ws_size,
                              hipStream_t stream) {
    const int* ei = (const int*)d_in[1];
    const int* ptr = (const int*)d_in[2];
    const float* emb = (const float*)d_in[3];
    const float* lin_w = (const float*)d_in[4];
    const float* att_s = (const float*)d_in[5];
    const float* att_d = (const float*)d_in[6];
    const float* w0 = (const float*)d_in[7];
    const float* b0 = (const float*)d_in[8];
    const float* w1 = (const float*)d_in[9];
    const float* b1 = (const float*)d_in[10];
    float* y = (float*)d_out;

    const int N = in_sizes[0];       // 50000
    const int E = in_sizes[1] / 2;   // 600000
    const int B = out_size;          // 128

    char* wp = (char*)d_ws;
    auto alloc = [&](size_t bytes) {
        void* p = (void*)wp;
        wp += (bytes + 255) & ~(size_t)255;
        return p;
    };
    float* h = (float*)alloc((size_t)N * DIM * 4);
    float* z = (float*)alloc((size_t)N * DIM * 4);
    float* a_s = (float*)alloc((size_t)N * HEADS * 4);
    float* a_d = (float*)alloc((size_t)N * HEADS * 4);
    int* deg = (int*)alloc((size_t)N * 4);
    int* rp = (int*)alloc((size_t)(N + 1) * 4);
    int* cur = (int*)alloc((size_t)N * 4);
    int* col = (int*)alloc((size_t)(E + N) * 4);
    int* part = (int*)alloc(64 * 4);
    int* partoff = (int*)alloc(64 * 4);
    float* z0 = (float*)alloc(DIM * 4);

    // CSR build (dst-grouped, self-loop appended per row)
    hipMemsetAsync(deg, 0, (size_t)N * 4, stream);
    k_count<<<(E + 255) / 256, 256, 0, stream>>>(ei, deg, E);
    int nb = (N + 1023) / 1024;
    k_scan_block<<<nb, 1024, 0, stream>>>(deg, rp, part, N);
    k_scan_part<<<1, 64, 0, stream>>>(part, partoff, nb);
    k_scan_add<<<(N + 255) / 256, 256, 0, stream>>>(rp, cur, col, deg, partoff, N);
    k_scatter<<<(E + 255) / 256, 256, 0, stream>>>(ei, cur, col, E);

    // layer 0 shortcut
    k_z0<<<1, DIM, 0, stream>>>(emb, lin_w, z0);
    k_hinit<<<(N * DIM + 255) / 256, 256, 0, stream>>>(emb, z0, rp, h, N);

    // layers 1..2
    for (int l = 1; l < 3; l++) {
        dim3 grid((N + BM - 1) / BM, DIM / BN);
        k_gemm<<<grid, 256, 0, stream>>>(h, lin_w + (size_t)l * DIM * DIM,
                                         att_s + (size_t)l * HEADS * DH,
                                         att_d + (size_t)l * HEADS * DH, z, a_s, a_d, N);
        k_aggr<<<N, 128, 0, stream>>>(z, a_s, a_d, rp, col, h, N);
    }

    // readout + MLP
    k_readout<<<B, 256, 0, stream>>>(h, ptr, w0, b0, w1, b1, y, N);
}

// Round 2
// 422.989 us; speedup vs baseline: 1.2527x; 1.2527x over previous
//
#include <hip/hip_runtime.h>
#include <math.h>

#define DIM 128
#define HEADS 4
#define NEG 0.2f

typedef unsigned short u16;
typedef unsigned int u32;
typedef short v8s __attribute__((ext_vector_type(8)));
typedef float v4f __attribute__((ext_vector_type(4)));

static __device__ __forceinline__ float lrelu(float x) { return x >= 0.f ? x : NEG * x; }
static __device__ __forceinline__ u16 f2bf(float f) {
    union { float f; u32 u; } v; v.f = f;
    u32 r = v.u + 0x7fffu + ((v.u >> 16) & 1u);
    return (u16)(r >> 16);
}

// ---------------- CSR build ----------------
__global__ void k_count(const int* __restrict__ ei, int* __restrict__ deg, int E) {
    int i = blockIdx.x * blockDim.x + threadIdx.x;
    if (i < E) atomicAdd(&deg[ei[E + i]], 1);
}

__global__ __launch_bounds__(1024) void k_scan_block(const int* __restrict__ deg,
                                                     int* __restrict__ rp1,
                                                     int* __restrict__ part, int N) {
    __shared__ int s[1024];
    int n = blockIdx.x * 1024 + threadIdx.x;
    int v = (n < N) ? (deg[n] + 1) : 0;   // +1 self-loop
    s[threadIdx.x] = v;
    __syncthreads();
    for (int off = 1; off < 1024; off <<= 1) {
        int t = 0;
        if (threadIdx.x >= off) t = s[threadIdx.x - off];
        __syncthreads();
        if (threadIdx.x >= off) s[threadIdx.x] += t;
        __syncthreads();
    }
    if (n < N) rp1[n + 1] = s[threadIdx.x];
    if (threadIdx.x == 1023) part[blockIdx.x] = s[1023];
}

__global__ void k_scan_part(const int* __restrict__ part, int* __restrict__ partoff, int nb) {
    int lane = threadIdx.x;
    int v = (lane < nb) ? part[lane] : 0;
    int orig = v;
    for (int off = 1; off < 64; off <<= 1) {
        int t = __shfl_up(v, off);
        if (lane >= off) v += t;
    }
    if (lane < nb) partoff[lane] = v - orig;
}

__global__ void k_scan_add(int* __restrict__ rp, int* __restrict__ cur, int* __restrict__ col,
                           const int* __restrict__ deg, const int* __restrict__ partoff, int N) {
    int n = blockIdx.x * blockDim.x + threadIdx.x;
    if (n >= N) return;
    int v = rp[n + 1] + partoff[n >> 10];
    rp[n + 1] = v;
    cur[n] = v - (deg[n] + 1);
    col[v - 1] = n;                // self-loop in last slot
    if (n == 0) rp[0] = 0;
}

__global__ void k_scatter(const int* __restrict__ ei, int* __restrict__ cur,
                          int* __restrict__ col, int E) {
    int i = blockIdx.x * blockDim.x + threadIdx.x;
    if (i < E) {
        int s = ei[i], d = ei[E + i];
        int p = atomicAdd(&cur[d], 1);
        col[p] = s;
    }
}

// ---------------- per-layer weight prep ----------------
// WT[l][n][k] = bf16(W[k][n]);  wv[l][c][j] = sum_d W[c][ (j&3)*32+d ] * att_{src|dst}[j&3][d]
__global__ void k_prep(const float* __restrict__ lin_w, const float* __restrict__ att_s,
                       const float* __restrict__ att_d, u16* __restrict__ WT,
                       float* __restrict__ wv) {
    int l = blockIdx.x;                                   // 0,1 -> layers 1,2
    const float* W = lin_w + (size_t)(l + 1) * DIM * DIM;
    for (int i = threadIdx.x; i < DIM * DIM; i += blockDim.x) {
        int k = i >> 7, n = i & 127;
        WT[(size_t)l * DIM * DIM + n * DIM + k] = f2bf(W[k * DIM + n]);
    }
    for (int i = threadIdx.x; i < DIM * 8; i += blockDim.x) {
        int c = i >> 3, j = i & 7;
        int hh = j & 3;
        const float* att = (j < 4) ? att_s : att_d;
        float s = 0.f;
        for (int d = 0; d < 32; d++)
            s += W[c * DIM + hh * 32 + d] * att[(size_t)(l + 1) * HEADS * 32 + hh * 32 + d];
        wv[(size_t)l * DIM * 8 + c * 8 + j] = s;
    }
}

// ---------------- layer 0 shortcut ----------------
__global__ void k_z0(const float* __restrict__ emb, const float* __restrict__ W0,
                     float* __restrict__ z0) {
    int c = threadIdx.x;
    float s = 0.f;
    for (int k = 0; k < DIM; k++) s += emb[k] * W0[k * DIM + c];
    z0[c] = s;
}

__global__ void k_hinit(const float* __restrict__ emb, const float* __restrict__ z0,
                        const int* __restrict__ rp, float* __restrict__ h,
                        u16* __restrict__ hb, int N) {
    int idx = blockIdx.x * blockDim.x + threadIdx.x;
    if (idx >= N * DIM) return;
    int n = idx >> 7, c = idx & 127;
    float degt = (float)(rp[n + 1] - rp[n]);
    float o = z0[c] * (1.f + degt);
    float e = o > 0.f ? o : (__expf(o) - 1.f);
    float v = e + emb[c];
    h[idx] = v;
    hb[idx] = f2bf(v);
}

// ---------------- fp32 attention logits: a = h @ wv ----------------
__global__ __launch_bounds__(256) void k_att(const float* __restrict__ h,
                                             const float* __restrict__ wv,
                                             float* __restrict__ a_s,
                                             float* __restrict__ a_d, int N) {
    int lane = threadIdx.x & 63;
    int n = blockIdx.x * 4 + (threadIdx.x >> 6);
    if (n >= N) return;
    float2 hv = *(const float2*)(h + (size_t)n * DIM + 2 * lane);
    const float* w0 = wv + (2 * lane) * 8;
    float p[8];
    #pragma unroll
    for (int j = 0; j < 8; j++) p[j] = hv.x * w0[j] + hv.y * w0[8 + j];
    #pragma unroll
    for (int off = 1; off < 64; off <<= 1) {
        #pragma unroll
        for (int j = 0; j < 8; j++) p[j] += __shfl_xor(p[j], off);
    }
    if (lane == 0) {
        #pragma unroll
        for (int j = 0; j < 4; j++) {
            a_s[(size_t)n * HEADS + j] = p[j];
            a_d[(size_t)n * HEADS + j] = p[4 + j];
        }
    }
}

// ---------------- bf16 MFMA GEMM: z = hb @ W  (z bf16 out) ----------------
#define GM 128
#define GN 64
#define LDK 136   // padded row stride in bf16 units

__global__ __launch_bounds__(256) void k_gemm(const u16* __restrict__ hb,
                                              const u16* __restrict__ WT,
                                              u16* __restrict__ z, int N) {
    __shared__ u16 As[GM * LDK];
    __shared__ u16 Bs[GN * LDK];
    int tid = threadIdx.x;
    int wave = tid >> 6, lane = tid & 63;
    int row0 = blockIdx.x * GM, col0 = blockIdx.y * GN;
    // stage A (128 rows x 128 k, bf16) and B (= W^T, 64 n-rows x 128 k)
    for (int i = tid; i < GM * 16; i += 256) {
        int r = i >> 4, seg = i & 15;
        int gr = row0 + r;
        uint4 v = make_uint4(0u, 0u, 0u, 0u);
        if (gr < N) v = *(const uint4*)(hb + (size_t)gr * DIM + seg * 8);
        *(uint4*)(As + r * LDK + seg * 8) = v;
    }
    for (int i = tid; i < GN * 16; i += 256) {
        int r = i >> 4, seg = i & 15;
        uint4 v = *(const uint4*)(WT + (size_t)(col0 + r) * DIM + seg * 8);
        *(uint4*)(Bs + r * LDK + seg * 8) = v;
    }
    __syncthreads();
    int wrow = wave * 32;
    int fr = lane & 15, quad = lane >> 4;
    v4f acc[2][4] = {};
    #pragma unroll
    for (int ks = 0; ks < 4; ks++) {
        v8s a[2], b[4];
        #pragma unroll
        for (int m = 0; m < 2; m++)
            a[m] = *(const v8s*)(As + (wrow + m * 16 + fr) * LDK + ks * 32 + quad * 8);
        #pragma unroll
        for (int n = 0; n < 4; n++)
            b[n] = *(const v8s*)(Bs + (n * 16 + fr) * LDK + ks * 32 + quad * 8);
        #pragma unroll
        for (int m = 0; m < 2; m++)
            #pragma unroll
            for (int n = 0; n < 4; n++)
                acc[m][n] = __builtin_amdgcn_mfma_f32_16x16x32_bf16(a[m], b[n], acc[m][n], 0, 0, 0);
    }
    // epilogue: D layout col=lane&15, row=quad*4+reg
    #pragma unroll
    for (int m = 0; m < 2; m++) {
        int rbase = row0 + wrow + m * 16 + quad * 4;
        #pragma unroll
        for (int n = 0; n < 4; n++) {
            int colg = col0 + n * 16 + fr;
            #pragma unroll
            for (int r = 0; r < 4; r++) {
                int gr = rbase + r;
                if (gr < N) z[(size_t)gr * DIM + colg] = f2bf(acc[m][n][r]);
            }
        }
    }
}

// ---------------- edge aggregation: 16 lanes/node, bf16 z gather ----------------
__global__ __launch_bounds__(256) void k_aggr(const u16* __restrict__ zb,
                                              const float* __restrict__ a_s,
                                              const float* __restrict__ a_d,
                                              const int* __restrict__ rp,
                                              const int* __restrict__ col,
                                              float* __restrict__ h,
                                              u16* __restrict__ hb, int N) {
    int tid = threadIdx.x;
    int g = tid & 15;                    // 8 channels per lane: 8g..8g+7
    int n = blockIdx.x * 16 + (tid >> 4);
    if (n >= N) return;
    int hh = g >> 2;                     // head of this lane's channels
    int beg = rp[n], end = rp[n + 1];
    float ad = a_d[(size_t)n * HEADS + hh];
    // pass 1: per-head max, edges split over the 4 lanes of the head group
    float amax = -1e30f;
    for (int j = beg + (g & 3); j < end; j += 4) {
        int s = col[j];
        amax = fmaxf(amax, lrelu(a_s[(size_t)s * HEADS + hh] + ad));
    }
    amax = fmaxf(amax, __shfl_xor(amax, 1));
    amax = fmaxf(amax, __shfl_xor(amax, 2));
    // pass 2: den + weighted/plain message sums
    float den = 0.f;
    float acc1[8] = {}, acc2[8] = {};
    for (int j = beg; j < end; j++) {
        int s = col[j];
        float a = lrelu(a_s[(size_t)s * HEADS + hh] + ad);
        float ex = __expf(a - amax);
        den += ex;
        uint4 zv = *(const uint4*)(zb + (size_t)s * DIM + 8 * g);
        u32 w[4] = {zv.x, zv.y, zv.z, zv.w};
        #pragma unroll
        for (int q = 0; q < 4; q++) {
            union { u32 u; float f; } lo, hi;
            lo.u = w[q] << 16;
            hi.u = w[q] & 0xffff0000u;
            acc1[2 * q] += lo.f * ex;     acc2[2 * q] += lo.f;
            acc1[2 * q + 1] += hi.f * ex; acc2[2 * q + 1] += hi.f;
        }
    }
    float inv = 1.f / den;
    size_t base = (size_t)n * DIM + 8 * g;
    float out[8];
    #pragma unroll
    for (int c = 0; c < 8; c++) {
        float o = acc1[c] * inv + acc2[c];
        float e = o > 0.f ? o : (__expf(o) - 1.f);
        out[c] = h[base + c] + e;
    }
    *(float4*)(h + base) = make_float4(out[0], out[1], out[2], out[3]);
    *(float4*)(h + base + 4) = make_float4(out[4], out[5], out[6], out[7]);
    uint4 hv;
    hv.x = (u32)f2bf(out[0]) | ((u32)f2bf(out[1]) << 16);
    hv.y = (u32)f2bf(out[2]) | ((u32)f2bf(out[3]) << 16);
    hv.z = (u32)f2bf(out[4]) | ((u32)f2bf(out[5]) << 16);
    hv.w = (u32)f2bf(out[6]) | ((u32)f2bf(out[7]) << 16);
    *(uint4*)(hb + base) = hv;
}

// ---------------- graph readout + MLP ----------------
__global__ __launch_bounds__(256) void k_readout(const float* __restrict__ h,
                                                 const int* __restrict__ ptr,
                                                 const float* __restrict__ w0,
                                                 const float* __restrict__ b0,
                                                 const float* __restrict__ w1,
                                                 const float* __restrict__ b1,
                                                 float* __restrict__ y, int N) {
    __shared__ float red[256];
    __shared__ float gsh[DIM];
    int b = blockIdx.x;
    int tid = threadIdx.x;
    int lo = 0, hi = N;
    while (lo < hi) { int m = (lo + hi) >> 1; if (ptr[m] < b) lo = m + 1; else hi = m; }
    int start = lo;
    hi = N;
    while (lo < hi) { int m = (lo + hi) >> 1; if (ptr[m] < b + 1) lo = m + 1; else hi = m; }
    int end = lo;
    int c = tid & 127, part = tid >> 7;
    float acc = 0.f;
    for (int n = start + part; n < end; n += 2) acc += h[(size_t)n * DIM + c];
    red[tid] = acc;
    __syncthreads();
    if (tid < DIM) {
        float s = red[tid] + red[tid + 128];
        float cnt = (float)(end - start);
        float gv = s / fmaxf(cnt, 1.f);
        gsh[tid] = fmaxf(gv, 0.f);
    }
    __syncthreads();
    if (tid < 64) {
        float hj = b0[tid];
        for (int k = 0; k < DIM; k++) hj += gsh[k] * w0[k * 64 + tid];
        hj = fmaxf(hj, 0.f);
        float p = hj * w1[tid];
        #pragma unroll
        for (int off = 32; off > 0; off >>= 1) p += __shfl_down(p, off);
        if (tid == 0) y[b] = p + b1[0];
    }
}

extern "C" void kernel_launch(void* const* d_in, const int* in_sizes, int n_in,
                              void* d_out, int out_size, void* d_ws, size_t ws_size,
                              hipStream_t stream) {
    const int* ei = (const int*)d_in[1];
    const int* ptr = (const int*)d_in[2];
    const float* emb = (const float*)d_in[3];
    const float* lin_w = (const float*)d_in[4];
    const float* att_s = (const float*)d_in[5];
    const float* att_d = (const float*)d_in[6];
    const float* w0 = (const float*)d_in[7];
    const float* b0 = (const float*)d_in[8];
    const float* w1 = (const float*)d_in[9];
    const float* b1 = (const float*)d_in[10];
    float* y = (float*)d_out;

    const int N = in_sizes[0];       // 50000
    const int E = in_sizes[1] / 2;   // 600000
    const int B = out_size;          // 128

    char* wp = (char*)d_ws;
    auto alloc = [&](size_t bytes) {
        void* p = (void*)wp;
        wp += (bytes + 255) & ~(size_t)255;
        return p;
    };
    float* h = (float*)alloc((size_t)N * DIM * 4);
    u16* hb = (u16*)alloc((size_t)N * DIM * 2);
    u16* zb = (u16*)alloc((size_t)N * DIM * 2);
    float* a_s = (float*)alloc((size_t)N * HEADS * 4);
    float* a_d = (float*)alloc((size_t)N * HEADS * 4);
    int* deg = (int*)alloc((size_t)N * 4);
    int* rp = (int*)alloc((size_t)(N + 1) * 4);
    int* cur = (int*)alloc((size_t)N * 4);
    int* col = (int*)alloc((size_t)(E + N) * 4);
    int* part = (int*)alloc(64 * 4);
    int* partoff = (int*)alloc(64 * 4);
    float* z0 = (float*)alloc(DIM * 4);
    u16* WT = (u16*)alloc((size_t)2 * DIM * DIM * 2);
    float* wv = (float*)alloc((size_t)2 * DIM * 8 * 4);

    // CSR build
    hipMemsetAsync(deg, 0, (size_t)N * 4, stream);
    k_count<<<(E + 255) / 256, 256, 0, stream>>>(ei, deg, E);
    int nb = (N + 1023) / 1024;
    k_scan_block<<<nb, 1024, 0, stream>>>(deg, rp, part, N);
    k_scan_part<<<1, 64, 0, stream>>>(part, partoff, nb);
    k_scan_add<<<(N + 255) / 256, 256, 0, stream>>>(rp, cur, col, deg, partoff, N);
    k_scatter<<<(E + 255) / 256, 256, 0, stream>>>(ei, cur, col, E);

    // weight prep + layer-0 shortcut
    k_prep<<<2, 256, 0, stream>>>(lin_w, att_s, att_d, WT, wv);
    k_z0<<<1, DIM, 0, stream>>>(emb, lin_w, z0);
    k_hinit<<<(N * DIM + 255) / 256, 256, 0, stream>>>(emb, z0, rp, h, hb, N);

    // layers 1..2
    for (int l = 0; l < 2; l++) {
        k_att<<<(N + 3) / 4, 256, 0, stream>>>(h, wv + (size_t)l * DIM * 8, a_s, a_d, N);
        dim3 grid((N + GM - 1) / GM, DIM / GN);
        k_gemm<<<grid, 256, 0, stream>>>(hb, WT + (size_t)l * DIM * DIM, zb, N);
        k_aggr<<<(N + 15) / 16, 256, 0, stream>>>(zb, a_s, a_d, rp, col, h, hb, N);
    }

    // readout + MLP
    k_readout<<<B, 256, 0, stream>>>(h, ptr, w0, b0, w1, b1, y, N);
}

// Round 3
// 387.764 us; speedup vs baseline: 1.3665x; 1.0908x over previous
//
#include <hip/hip_runtime.h>
#include <math.h>

#define DIM 128
#define HEADS 4
#define NEG 0.2f

typedef unsigned short u16;
typedef unsigned int u32;
typedef short v8s __attribute__((ext_vector_type(8)));
typedef float v4f __attribute__((ext_vector_type(4)));

static __device__ __forceinline__ float lrelu(float x) { return x >= 0.f ? x : NEG * x; }
static __device__ __forceinline__ u16 f2bf(float f) {
    union { float f; u32 u; } v; v.f = f;
    u32 r = v.u + 0x7fffu + ((v.u >> 16) & 1u);
    return (u16)(r >> 16);
}
static __device__ __forceinline__ float bf2f(u16 b) {
    union { u32 u; float f; } v; v.u = ((u32)b) << 16;
    return v.f;
}
static __device__ __forceinline__ void splitbf(float x, u16& hi, u16& lo) {
    hi = f2bf(x);
    lo = f2bf(x - bf2f(hi));
}

// ---------------- CSR build ----------------
__global__ void k_count(const int* __restrict__ ei, int* __restrict__ deg, int E) {
    int i = blockIdx.x * blockDim.x + threadIdx.x;
    if (i < E) atomicAdd(&deg[ei[E + i]], 1);
}

__global__ __launch_bounds__(1024) void k_scan_block(const int* __restrict__ deg,
                                                     int* __restrict__ rp1,
                                                     int* __restrict__ part, int N) {
    __shared__ int s[1024];
    int n = blockIdx.x * 1024 + threadIdx.x;
    int v = (n < N) ? (deg[n] + 1) : 0;   // +1 self-loop
    s[threadIdx.x] = v;
    __syncthreads();
    for (int off = 1; off < 1024; off <<= 1) {
        int t = 0;
        if (threadIdx.x >= off) t = s[threadIdx.x - off];
        __syncthreads();
        if (threadIdx.x >= off) s[threadIdx.x] += t;
        __syncthreads();
    }
    if (n < N) rp1[n + 1] = s[threadIdx.x];
    if (threadIdx.x == 1023) part[blockIdx.x] = s[1023];
}

__global__ void k_scan_part(const int* __restrict__ part, int* __restrict__ partoff, int nb) {
    int lane = threadIdx.x;
    int v = (lane < nb) ? part[lane] : 0;
    int orig = v;
    for (int off = 1; off < 64; off <<= 1) {
        int t = __shfl_up(v, off);
        if (lane >= off) v += t;
    }
    if (lane < nb) partoff[lane] = v - orig;
}

__global__ void k_scan_add(int* __restrict__ rp, int* __restrict__ cur, int* __restrict__ col,
                           const int* __restrict__ deg, const int* __restrict__ partoff, int N) {
    int n = blockIdx.x * blockDim.x + threadIdx.x;
    if (n >= N) return;
    int v = rp[n + 1] + partoff[n >> 10];
    rp[n + 1] = v;
    cur[n] = v - (deg[n] + 1);
    col[v - 1] = n;                // self-loop in last slot
    if (n == 0) rp[0] = 0;
}

__global__ void k_scatter(const int* __restrict__ ei, int* __restrict__ cur,
                          int* __restrict__ col, int E) {
    int i = blockIdx.x * blockDim.x + threadIdx.x;
    if (i < E) {
        int s = ei[i], d = ei[E + i];
        int p = atomicAdd(&cur[d], 1);
        col[p] = s;
    }
}

// ---------------- per-layer weight prep ----------------
__global__ void k_prep(const float* __restrict__ lin_w, const float* __restrict__ att_s,
                       const float* __restrict__ att_d, u16* __restrict__ WTh,
                       u16* __restrict__ WTl, float* __restrict__ wv) {
    int l = blockIdx.x;                                   // 0,1 -> GAT layers 1,2
    const float* W = lin_w + (size_t)(l + 1) * DIM * DIM;
    for (int i = threadIdx.x; i < DIM * DIM; i += blockDim.x) {
        int k = i >> 7, n = i & 127;
        u16 hi, lo;
        splitbf(W[k * DIM + n], hi, lo);
        WTh[(size_t)l * DIM * DIM + n * DIM + k] = hi;
        WTl[(size_t)l * DIM * DIM + n * DIM + k] = lo;
    }
    for (int i = threadIdx.x; i < DIM * 8; i += blockDim.x) {
        int c = i >> 3, j = i & 7;
        int hh = j & 3;
        const float* att = (j < 4) ? att_s : att_d;
        float s = 0.f;
        for (int d = 0; d < 32; d++)
            s += W[c * DIM + hh * 32 + d] * att[(size_t)(l + 1) * HEADS * 32 + hh * 32 + d];
        wv[(size_t)l * DIM * 8 + c * 8 + j] = s;
    }
}

// ---------------- layer 0 shortcut ----------------
__global__ void k_z0(const float* __restrict__ emb, const float* __restrict__ W0,
                     float* __restrict__ z0) {
    int c = threadIdx.x;
    float s = 0.f;
    for (int k = 0; k < DIM; k++) s += emb[k] * W0[k * DIM + c];
    z0[c] = s;
}

// 16 lanes/node: h0 = elu(z0*(1+deg)) + emb; also fused layer-1 attention logits
__global__ __launch_bounds__(256) void k_hinit(const float* __restrict__ emb,
                                               const float* __restrict__ z0,
                                               const int* __restrict__ rp,
                                               const float* __restrict__ wv,
                                               float* __restrict__ h, u16* __restrict__ hb,
                                               u16* __restrict__ hl, float* __restrict__ a_s,
                                               float* __restrict__ a_d, int N) {
    int tid = threadIdx.x;
    int g = tid & 15;
    int n = blockIdx.x * 16 + (tid >> 4);
    if (n >= N) return;
    float degt = (float)(rp[n + 1] - rp[n]);
    int c0 = 8 * g;
    float out[8];
    #pragma unroll
    for (int c = 0; c < 8; c++) {
        float o = z0[c0 + c] * (1.f + degt);
        float e = o > 0.f ? o : (__expf(o) - 1.f);
        out[c] = e + emb[c0 + c];
    }
    size_t base = (size_t)n * DIM + c0;
    *(float4*)(h + base) = make_float4(out[0], out[1], out[2], out[3]);
    *(float4*)(h + base + 4) = make_float4(out[4], out[5], out[6], out[7]);
    u16 hi[8], lo[8];
    #pragma unroll
    for (int c = 0; c < 8; c++) splitbf(out[c], hi[c], lo[c]);
    uint4 hv, lv;
    hv.x = (u32)hi[0] | ((u32)hi[1] << 16); hv.y = (u32)hi[2] | ((u32)hi[3] << 16);
    hv.z = (u32)hi[4] | ((u32)hi[5] << 16); hv.w = (u32)hi[6] | ((u32)hi[7] << 16);
    lv.x = (u32)lo[0] | ((u32)lo[1] << 16); lv.y = (u32)lo[2] | ((u32)lo[3] << 16);
    lv.z = (u32)lo[4] | ((u32)lo[5] << 16); lv.w = (u32)lo[6] | ((u32)lo[7] << 16);
    *(uint4*)(hb + base) = hv;
    *(uint4*)(hl + base) = lv;
    // fused attention logits for layer 1 (exact fp32)
    float p[8] = {};
    #pragma unroll
    for (int c = 0; c < 8; c++) {
        const float* w = wv + (c0 + c) * 8;
        #pragma unroll
        for (int j = 0; j < 8; j++) p[j] += out[c] * w[j];
    }
    #pragma unroll
    for (int off = 1; off < 16; off <<= 1)
        #pragma unroll
        for (int j = 0; j < 8; j++) p[j] += __shfl_xor(p[j], off);
    if (g == 0) {
        #pragma unroll
        for (int j = 0; j < 4; j++) {
            a_s[(size_t)n * HEADS + j] = p[j];
            a_d[(size_t)n * HEADS + j] = p[4 + j];
        }
    }
}

// ---------------- split-bf16 MFMA GEMM: z = (hh+hl) @ (Wh+Wl), fp32-accurate ----------------
#define GM 64
#define GN 64
#define LDK 136   // padded row stride in bf16 units

__global__ __launch_bounds__(256) void k_gemm(const u16* __restrict__ hb,
                                              const u16* __restrict__ hlg,
                                              const u16* __restrict__ WTh,
                                              const u16* __restrict__ WTl,
                                              u16* __restrict__ z, int N) {
    __shared__ u16 Ah[GM * LDK];
    __shared__ u16 Al[GM * LDK];
    __shared__ u16 Bh[GN * LDK];
    __shared__ u16 Bl[GN * LDK];
    int tid = threadIdx.x;
    int wave = tid >> 6, lane = tid & 63;
    int row0 = blockIdx.x * GM, col0 = blockIdx.y * GN;
    for (int i = tid; i < GM * 16; i += 256) {
        int r = i >> 4, seg = i & 15;
        int gr = row0 + r;
        uint4 vh = make_uint4(0u, 0u, 0u, 0u), vl = vh;
        if (gr < N) {
            vh = *(const uint4*)(hb + (size_t)gr * DIM + seg * 8);
            vl = *(const uint4*)(hlg + (size_t)gr * DIM + seg * 8);
        }
        *(uint4*)(Ah + r * LDK + seg * 8) = vh;
        *(uint4*)(Al + r * LDK + seg * 8) = vl;
    }
    for (int i = tid; i < GN * 16; i += 256) {
        int r = i >> 4, seg = i & 15;
        *(uint4*)(Bh + r * LDK + seg * 8) = *(const uint4*)(WTh + (size_t)(col0 + r) * DIM + seg * 8);
        *(uint4*)(Bl + r * LDK + seg * 8) = *(const uint4*)(WTl + (size_t)(col0 + r) * DIM + seg * 8);
    }
    __syncthreads();
    int wrow = wave * 16;
    int fr = lane & 15, quad = lane >> 4;
    v4f acc[4] = {};
    #pragma unroll
    for (int ks = 0; ks < 4; ks++) {
        v8s ah = *(const v8s*)(Ah + (wrow + fr) * LDK + ks * 32 + quad * 8);
        v8s al = *(const v8s*)(Al + (wrow + fr) * LDK + ks * 32 + quad * 8);
        #pragma unroll
        for (int n = 0; n < 4; n++) {
            v8s bh = *(const v8s*)(Bh + (n * 16 + fr) * LDK + ks * 32 + quad * 8);
            v8s bl = *(const v8s*)(Bl + (n * 16 + fr) * LDK + ks * 32 + quad * 8);
            acc[n] = __builtin_amdgcn_mfma_f32_16x16x32_bf16(ah, bh, acc[n], 0, 0, 0);
            acc[n] = __builtin_amdgcn_mfma_f32_16x16x32_bf16(ah, bl, acc[n], 0, 0, 0);
            acc[n] = __builtin_amdgcn_mfma_f32_16x16x32_bf16(al, bh, acc[n], 0, 0, 0);
        }
    }
    // D layout: col=lane&15, row=quad*4+reg
    int rbase = row0 + wrow + quad * 4;
    #pragma unroll
    for (int n = 0; n < 4; n++) {
        int colg = col0 + n * 16 + fr;
        #pragma unroll
        for (int r = 0; r < 4; r++) {
            int gr = rbase + r;
            if (gr < N) z[(size_t)gr * DIM + colg] = f2bf(acc[n][r]);
        }
    }
}

// ---------------- edge aggregation + fused next-layer logits ----------------
__global__ __launch_bounds__(256) void k_aggr(const u16* __restrict__ zb,
                                              const float* __restrict__ a_s,
                                              const float* __restrict__ a_d,
                                              const int* __restrict__ rp,
                                              const int* __restrict__ col,
                                              float* __restrict__ h, u16* __restrict__ hb,
                                              u16* __restrict__ hl,
                                              const float* __restrict__ wvn,
                                              float* __restrict__ as_out,
                                              float* __restrict__ ad_out, int N) {
    int tid = threadIdx.x;
    int g = tid & 15;                    // 8 channels per lane
    int n = blockIdx.x * 16 + (tid >> 4);
    if (n >= N) return;
    int hh = g >> 2;
    int beg = rp[n], end = rp[n + 1];
    float ad = a_d[(size_t)n * HEADS + hh];
    float amax = -1e30f;
    for (int j = beg + (g & 3); j < end; j += 4) {
        int s = col[j];
        amax = fmaxf(amax, lrelu(a_s[(size_t)s * HEADS + hh] + ad));
    }
    amax = fmaxf(amax, __shfl_xor(amax, 1));
    amax = fmaxf(amax, __shfl_xor(amax, 2));
    float den = 0.f;
    float acc1[8] = {}, acc2[8] = {};
    for (int j = beg; j < end; j++) {
        int s = col[j];
        float a = lrelu(a_s[(size_t)s * HEADS + hh] + ad);
        float ex = __expf(a - amax);
        den += ex;
        uint4 zv = *(const uint4*)(zb + (size_t)s * DIM + 8 * g);
        u32 w[4] = {zv.x, zv.y, zv.z, zv.w};
        #pragma unroll
        for (int q = 0; q < 4; q++) {
            union { u32 u; float f; } lo, hi;
            lo.u = w[q] << 16;
            hi.u = w[q] & 0xffff0000u;
            acc1[2 * q] += lo.f * ex;     acc2[2 * q] += lo.f;
            acc1[2 * q + 1] += hi.f * ex; acc2[2 * q + 1] += hi.f;
        }
    }
    float inv = 1.f / den;
    size_t base = (size_t)n * DIM + 8 * g;
    float out[8];
    #pragma unroll
    for (int c = 0; c < 8; c++) {
        float o = acc1[c] * inv + acc2[c];
        float e = o > 0.f ? o : (__expf(o) - 1.f);
        out[c] = h[base + c] + e;
    }
    *(float4*)(h + base) = make_float4(out[0], out[1], out[2], out[3]);
    *(float4*)(h + base + 4) = make_float4(out[4], out[5], out[6], out[7]);
    u16 chi[8], clo[8];
    #pragma unroll
    for (int c = 0; c < 8; c++) splitbf(out[c], chi[c], clo[c]);
    uint4 hv, lv;
    hv.x = (u32)chi[0] | ((u32)chi[1] << 16); hv.y = (u32)chi[2] | ((u32)chi[3] << 16);
    hv.z = (u32)chi[4] | ((u32)chi[5] << 16); hv.w = (u32)chi[6] | ((u32)chi[7] << 16);
    lv.x = (u32)clo[0] | ((u32)clo[1] << 16); lv.y = (u32)clo[2] | ((u32)clo[3] << 16);
    lv.z = (u32)clo[4] | ((u32)clo[5] << 16); lv.w = (u32)clo[6] | ((u32)clo[7] << 16);
    *(uint4*)(hb + base) = hv;
    *(uint4*)(hl + base) = lv;
    if (wvn) {   // fused next-layer attention logits (exact fp32)
        float p[8] = {};
        int c0 = 8 * g;
        #pragma unroll
        for (int c = 0; c < 8; c++) {
            const float* w = wvn + (c0 + c) * 8;
            #pragma unroll
            for (int j = 0; j < 8; j++) p[j] += out[c] * w[j];
        }
        #pragma unroll
        for (int off = 1; off < 16; off <<= 1)
            #pragma unroll
            for (int j = 0; j < 8; j++) p[j] += __shfl_xor(p[j], off);
        if (g == 0) {
            #pragma unroll
            for (int j = 0; j < 4; j++) {
                as_out[(size_t)n * HEADS + j] = p[j];
                ad_out[(size_t)n * HEADS + j] = p[4 + j];
            }
        }
    }
}

// ---------------- readout phase 1: run-length segment sum, few atomics ----------------
__global__ __launch_bounds__(256) void k_red1(const float* __restrict__ h,
                                              const int* __restrict__ ptr,
                                              float* __restrict__ g, int N) {
    int tid = threadIdx.x;
    int c = tid & 127, half = tid >> 7;
    int n0 = blockIdx.x * 64;
    int nend = n0 + 64 < N ? n0 + 64 : N;
    float acc = 0.f;
    int cur = -1;
    for (int n = n0 + half; n < nend; n += 2) {
        int gid = ptr[n];
        if (gid != cur) {
            if (cur >= 0) atomicAdd(&g[(size_t)cur * DIM + c], acc);
            cur = gid;
            acc = 0.f;
        }
        acc += h[(size_t)n * DIM + c];
    }
    if (cur >= 0) atomicAdd(&g[(size_t)cur * DIM + c], acc);
}

// ---------------- readout phase 2: mean + relu + MLP ----------------
__global__ __launch_bounds__(128) void k_red2(const float* __restrict__ g,
                                              const int* __restrict__ ptr,
                                              const float* __restrict__ w0,
                                              const float* __restrict__ b0,
                                              const float* __restrict__ w1,
                                              const float* __restrict__ b1,
                                              float* __restrict__ y, int N) {
    __shared__ float gsh[DIM];
    int b = blockIdx.x;
    int tid = threadIdx.x;
    int lo = 0, hi = N;
    while (lo < hi) { int m = (lo + hi) >> 1; if (ptr[m] < b) lo = m + 1; else hi = m; }
    int start = lo;
    hi = N;
    while (lo < hi) { int m = (lo + hi) >> 1; if (ptr[m] < b + 1) lo = m + 1; else hi = m; }
    int end = lo;
    float cnt = (float)(end - start);
    float gv = g[(size_t)b * DIM + tid] / fmaxf(cnt, 1.f);
    gsh[tid] = fmaxf(gv, 0.f);
    __syncthreads();
    if (tid < 64) {
        float hj = b0[tid];
        for (int k = 0; k < DIM; k++) hj += gsh[k] * w0[k * 64 + tid];
        hj = fmaxf(hj, 0.f);
        float p = hj * w1[tid];
        #pragma unroll
        for (int off = 32; off > 0; off >>= 1) p += __shfl_down(p, off);
        if (tid == 0) y[b] = p + b1[0];
    }
}

extern "C" void kernel_launch(void* const* d_in, const int* in_sizes, int n_in,
                              void* d_out, int out_size, void* d_ws, size_t ws_size,
                              hipStream_t stream) {
    const int* ei = (const int*)d_in[1];
    const int* ptr = (const int*)d_in[2];
    const float* emb = (const float*)d_in[3];
    const float* lin_w = (const float*)d_in[4];
    const float* att_s = (const float*)d_in[5];
    const float* att_d = (const float*)d_in[6];
    const float* w0 = (const float*)d_in[7];
    const float* b0 = (const float*)d_in[8];
    const float* w1 = (const float*)d_in[9];
    const float* b1 = (const float*)d_in[10];
    float* y = (float*)d_out;

    const int N = in_sizes[0];       // 50000
    const int E = in_sizes[1] / 2;   // 600000
    const int B = out_size;          // 128

    char* wp = (char*)d_ws;
    auto alloc = [&](size_t bytes) {
        void* p = (void*)wp;
        wp += (bytes + 255) & ~(size_t)255;
        return p;
    };
    float* h = (float*)alloc((size_t)N * DIM * 4);
    u16* hb = (u16*)alloc((size_t)N * DIM * 2);
    u16* hl = (u16*)alloc((size_t)N * DIM * 2);
    u16* zb = (u16*)alloc((size_t)N * DIM * 2);
    float* a_s0 = (float*)alloc((size_t)N * HEADS * 4);
    float* a_d0 = (float*)alloc((size_t)N * HEADS * 4);
    float* a_s1 = (float*)alloc((size_t)N * HEADS * 4);
    float* a_d1 = (float*)alloc((size_t)N * HEADS * 4);
    int* deg = (int*)alloc((size_t)N * 4);
    int* rp = (int*)alloc((size_t)(N + 1) * 4);
    int* cur = (int*)alloc((size_t)N * 4);
    int* col = (int*)alloc((size_t)(E + N) * 4);
    int* part = (int*)alloc(64 * 4);
    int* partoff = (int*)alloc(64 * 4);
    float* z0 = (float*)alloc(DIM * 4);
    u16* WTh = (u16*)alloc((size_t)2 * DIM * DIM * 2);
    u16* WTl = (u16*)alloc((size_t)2 * DIM * DIM * 2);
    float* wv = (float*)alloc((size_t)2 * DIM * 8 * 4);
    float* gbuf = (float*)alloc((size_t)B * DIM * 4);

    // CSR build
    hipMemsetAsync(deg, 0, (size_t)N * 4, stream);
    hipMemsetAsync(gbuf, 0, (size_t)B * DIM * 4, stream);
    k_count<<<(E + 255) / 256, 256, 0, stream>>>(ei, deg, E);
    int nb = (N + 1023) / 1024;
    k_scan_block<<<nb, 1024, 0, stream>>>(deg, rp, part, N);
    k_scan_part<<<1, 64, 0, stream>>>(part, partoff, nb);
    k_scan_add<<<(N + 255) / 256, 256, 0, stream>>>(rp, cur, col, deg, partoff, N);
    k_scatter<<<(E + 255) / 256, 256, 0, stream>>>(ei, cur, col, E);

    // weight prep + layer-0 shortcut (fused layer-1 logits)
    k_prep<<<2, 256, 0, stream>>>(lin_w, att_s, att_d, WTh, WTl, wv);
    k_z0<<<1, DIM, 0, stream>>>(emb, lin_w, z0);
    k_hinit<<<(N + 15) / 16, 256, 0, stream>>>(emb, z0, rp, wv, h, hb, hl, a_s0, a_d0, N);

    // GAT layers 1..2
    dim3 grid((N + GM - 1) / GM, DIM / GN);
    k_gemm<<<grid, 256, 0, stream>>>(hb, hl, WTh, WTl, zb, N);
    k_aggr<<<(N + 15) / 16, 256, 0, stream>>>(zb, a_s0, a_d0, rp, col, h, hb, hl,
                                              wv + (size_t)DIM * 8, a_s1, a_d1, N);
    k_gemm<<<grid, 256, 0, stream>>>(hb, hl, WTh + (size_t)DIM * DIM,
                                     WTl + (size_t)DIM * DIM, zb, N);
    k_aggr<<<(N + 15) / 16, 256, 0, stream>>>(zb, a_s1, a_d1, rp, col, h, hb, hl,
                                              nullptr, nullptr, nullptr, N);

    // readout + MLP
    k_red1<<<(N + 63) / 64, 256, 0, stream>>>(h, ptr, gbuf, N);
    k_red2<<<B, 128, 0, stream>>>(gbuf, ptr, w0, b0, w1, b1, y, N);
}

// Round 4
// 357.473 us; speedup vs baseline: 1.4822x; 1.0847x over previous
//
#include <hip/hip_runtime.h>
#include <math.h>

#define DIM 128
#define HEADS 4
#define NEG 0.2f

typedef unsigned short u16;
typedef unsigned int u32;
typedef short v8s __attribute__((ext_vector_type(8)));
typedef float v4f __attribute__((ext_vector_type(4)));

static __device__ __forceinline__ float lrelu(float x) { return x >= 0.f ? x : NEG * x; }
static __device__ __forceinline__ u16 f2bf(float f) {
    union { float f; u32 u; } v; v.f = f;
    u32 r = v.u + 0x7fffu + ((v.u >> 16) & 1u);
    return (u16)(r >> 16);
}
static __device__ __forceinline__ float bf2f(u16 b) {
    union { u32 u; float f; } v; v.u = ((u32)b) << 16;
    return v.f;
}
static __device__ __forceinline__ void splitbf(float x, u16& hi, u16& lo) {
    hi = f2bf(x);
    lo = f2bf(x - bf2f(hi));
}

// ---------------- CSR build ----------------
__global__ void k_count(const int* __restrict__ ei, int* __restrict__ deg, int E) {
    int i = blockIdx.x * blockDim.x + threadIdx.x;
    if (i < E) atomicAdd(&deg[ei[E + i]], 1);
}

__global__ __launch_bounds__(1024) void k_scan_block(const int* __restrict__ deg,
                                                     int* __restrict__ rp1,
                                                     int* __restrict__ part, int N) {
    __shared__ int s[1024];
    int n = blockIdx.x * 1024 + threadIdx.x;
    int v = (n < N) ? (deg[n] + 1) : 0;   // +1 self-loop
    s[threadIdx.x] = v;
    __syncthreads();
    for (int off = 1; off < 1024; off <<= 1) {
        int t = 0;
        if (threadIdx.x >= off) t = s[threadIdx.x - off];
        __syncthreads();
        if (threadIdx.x >= off) s[threadIdx.x] += t;
        __syncthreads();
    }
    if (n < N) rp1[n + 1] = s[threadIdx.x];
    if (threadIdx.x == 1023) part[blockIdx.x] = s[1023];
}

__global__ void k_scan_part(const int* __restrict__ part, int* __restrict__ partoff, int nb) {
    int lane = threadIdx.x;
    int v = (lane < nb) ? part[lane] : 0;
    int orig = v;
    for (int off = 1; off < 64; off <<= 1) {
        int t = __shfl_up(v, off);
        if (lane >= off) v += t;
    }
    if (lane < nb) partoff[lane] = v - orig;
}

__global__ void k_scan_add(int* __restrict__ rp, int* __restrict__ cur, int* __restrict__ col,
                           const int* __restrict__ deg, const int* __restrict__ partoff, int N) {
    int n = blockIdx.x * blockDim.x + threadIdx.x;
    if (n >= N) return;
    int v = rp[n + 1] + partoff[n >> 10];
    rp[n + 1] = v;
    cur[n] = v - (deg[n] + 1);
    col[v - 1] = n;                // self-loop in last slot
    if (n == 0) rp[0] = 0;
}

__global__ void k_scatter(const int* __restrict__ ei, int* __restrict__ cur,
                          int* __restrict__ col, int E) {
    int i = blockIdx.x * blockDim.x + threadIdx.x;
    if (i < E) {
        int s = ei[i], d = ei[E + i];
        int p = atomicAdd(&cur[d], 1);
        col[p] = s;
    }
}

// ---------------- per-layer weight prep ----------------
__global__ void k_prep(const float* __restrict__ lin_w, const float* __restrict__ att_s,
                       const float* __restrict__ att_d, u16* __restrict__ WTh,
                       u16* __restrict__ WTl, float* __restrict__ wv) {
    int l = blockIdx.x;                                   // 0,1 -> GAT layers 1,2
    const float* W = lin_w + (size_t)(l + 1) * DIM * DIM;
    for (int i = threadIdx.x; i < DIM * DIM; i += blockDim.x) {
        int k = i >> 7, n = i & 127;
        u16 hi, lo;
        splitbf(W[k * DIM + n], hi, lo);
        WTh[(size_t)l * DIM * DIM + n * DIM + k] = hi;
        WTl[(size_t)l * DIM * DIM + n * DIM + k] = lo;
    }
    for (int i = threadIdx.x; i < DIM * 8; i += blockDim.x) {
        int c = i >> 3, j = i & 7;
        int hh = j & 3;
        const float* att = (j < 4) ? att_s : att_d;
        float s = 0.f;
        for (int d = 0; d < 32; d++)
            s += W[c * DIM + hh * 32 + d] * att[(size_t)(l + 1) * HEADS * 32 + hh * 32 + d];
        wv[(size_t)l * DIM * 8 + c * 8 + j] = s;
    }
}

// ---------------- layer 0 shortcut ----------------
__global__ void k_z0(const float* __restrict__ emb, const float* __restrict__ W0,
                     float* __restrict__ z0) {
    int c = threadIdx.x;
    float s = 0.f;
    for (int k = 0; k < DIM; k++) s += emb[k] * W0[k * DIM + c];
    z0[c] = s;
}

// 16 lanes/node: h0 = elu(z0*(1+deg)) + emb; fused layer-1 attention logits
__global__ __launch_bounds__(256) void k_hinit(const float* __restrict__ emb,
                                               const float* __restrict__ z0,
                                               const int* __restrict__ rp,
                                               const float* __restrict__ wv,
                                               float* __restrict__ h, float* __restrict__ a_s,
                                               float* __restrict__ a_d, int N) {
    int tid = threadIdx.x;
    int g = tid & 15;
    int n = blockIdx.x * 16 + (tid >> 4);
    if (n >= N) return;
    float degt = (float)(rp[n + 1] - rp[n]);
    int c0 = 8 * g;
    float out[8];
    #pragma unroll
    for (int c = 0; c < 8; c++) {
        float o = z0[c0 + c] * (1.f + degt);
        float e = o > 0.f ? o : (__expf(o) - 1.f);
        out[c] = e + emb[c0 + c];
    }
    size_t base = (size_t)n * DIM + c0;
    *(float4*)(h + base) = make_float4(out[0], out[1], out[2], out[3]);
    *(float4*)(h + base + 4) = make_float4(out[4], out[5], out[6], out[7]);
    // fused attention logits for layer 1 (exact fp32)
    float p[8] = {};
    #pragma unroll
    for (int c = 0; c < 8; c++) {
        const float* w = wv + (c0 + c) * 8;
        #pragma unroll
        for (int j = 0; j < 8; j++) p[j] += out[c] * w[j];
    }
    #pragma unroll
    for (int off = 1; off < 16; off <<= 1)
        #pragma unroll
        for (int j = 0; j < 8; j++) p[j] += __shfl_xor(p[j], off);
    if (g == 0) {
        #pragma unroll
        for (int j = 0; j < 4; j++) {
            a_s[(size_t)n * HEADS + j] = p[j];
            a_d[(size_t)n * HEADS + j] = p[4 + j];
        }
    }
}

// ---------------- split-bf16 MFMA GEMM: z = h @ (Wh+Wl), A split in-regs ----------------
#define GM 64
#define LDA 132   // fp32 row stride for A
#define LDB 136   // bf16 row stride for B

__global__ __launch_bounds__(256) void k_gemm(const float* __restrict__ h,
                                              const u16* __restrict__ WTh,
                                              const u16* __restrict__ WTl,
                                              u16* __restrict__ z, int N) {
    __shared__ float As[GM * LDA];
    __shared__ u16 Bh[64 * LDB];
    __shared__ u16 Bl[64 * LDB];
    int tid = threadIdx.x;
    int wave = tid >> 6, lane = tid & 63;
    int row0 = blockIdx.x * GM;
    // stage A fp32 (once)
    for (int i = tid; i < GM * 32; i += 256) {
        int r = i >> 5, seg = i & 31;
        int gr = row0 + r;
        float4 v = make_float4(0.f, 0.f, 0.f, 0.f);
        if (gr < N) v = *(const float4*)(h + (size_t)gr * DIM + seg * 4);
        *(float4*)(As + r * LDA + seg * 4) = v;
    }
    // stage B tile 0
    for (int i = tid; i < 64 * 16; i += 256) {
        int r = i >> 4, seg = i & 15;
        *(uint4*)(Bh + r * LDB + seg * 8) = *(const uint4*)(WTh + (size_t)r * DIM + seg * 8);
        *(uint4*)(Bl + r * LDB + seg * 8) = *(const uint4*)(WTl + (size_t)r * DIM + seg * 8);
    }
    __syncthreads();
    int wrow = wave * 16;
    int fr = lane & 15, quad = lane >> 4;
    // load + split A fragments once (trunc-hi + RTNE-lo; dropped al*bl term ~2^-17)
    v8s ah[4], al[4];
    #pragma unroll
    for (int ks = 0; ks < 4; ks++) {
        const float* src = As + (wrow + fr) * LDA + ks * 32 + quad * 8;
        #pragma unroll
        for (int e = 0; e < 8; e++) {
            union { float f; u32 u; } v; v.f = src[e];
            u32 xh = v.u & 0xffff0000u;
            ah[ks][e] = (short)(xh >> 16);
            union { u32 u; float f; } rr; rr.u = xh;
            al[ks][e] = (short)f2bf(v.f - rr.f);
        }
    }
    #pragma unroll
    for (int t = 0; t < 2; t++) {
        if (t == 1) {
            __syncthreads();
            for (int i = tid; i < 64 * 16; i += 256) {
                int r = i >> 4, seg = i & 15;
                *(uint4*)(Bh + r * LDB + seg * 8) = *(const uint4*)(WTh + (size_t)(64 + r) * DIM + seg * 8);
                *(uint4*)(Bl + r * LDB + seg * 8) = *(const uint4*)(WTl + (size_t)(64 + r) * DIM + seg * 8);
            }
            __syncthreads();
        }
        v4f acc[4] = {};
        #pragma unroll
        for (int ks = 0; ks < 4; ks++) {
            #pragma unroll
            for (int nn = 0; nn < 4; nn++) {
                v8s bh = *(const v8s*)(Bh + (nn * 16 + fr) * LDB + ks * 32 + quad * 8);
                v8s bl = *(const v8s*)(Bl + (nn * 16 + fr) * LDB + ks * 32 + quad * 8);
                acc[nn] = __builtin_amdgcn_mfma_f32_16x16x32_bf16(ah[ks], bh, acc[nn], 0, 0, 0);
                acc[nn] = __builtin_amdgcn_mfma_f32_16x16x32_bf16(ah[ks], bl, acc[nn], 0, 0, 0);
                acc[nn] = __builtin_amdgcn_mfma_f32_16x16x32_bf16(al[ks], bh, acc[nn], 0, 0, 0);
            }
        }
        // D layout: col=lane&15, row=quad*4+reg
        int rbase = row0 + wrow + quad * 4;
        int col0 = t * 64;
        #pragma unroll
        for (int nn = 0; nn < 4; nn++) {
            int colg = col0 + nn * 16 + fr;
            #pragma unroll
            for (int r = 0; r < 4; r++) {
                int gr = rbase + r;
                if (gr < N) z[(size_t)gr * DIM + colg] = f2bf(acc[nn][r]);
            }
        }
    }
}

// ---------------- edge aggregation (unrolled gathers) + optional fused readout ----------------
static __device__ __forceinline__ void accum8(uint4 zv, float ex, float* acc1, float* acc2) {
    u32 w[4] = {zv.x, zv.y, zv.z, zv.w};
    #pragma unroll
    for (int q = 0; q < 4; q++) {
        union { u32 u; float f; } lo, hi;
        lo.u = w[q] << 16;
        hi.u = w[q] & 0xffff0000u;
        acc1[2 * q] += lo.f * ex;     acc2[2 * q] += lo.f;
        acc1[2 * q + 1] += hi.f * ex; acc2[2 * q + 1] += hi.f;
    }
}

__global__ __launch_bounds__(256) void k_aggr(const u16* __restrict__ zb,
                                              const float* __restrict__ a_s,
                                              const float* __restrict__ a_d,
                                              const int* __restrict__ rp,
                                              const int* __restrict__ col,
                                              float* __restrict__ h,
                                              const float* __restrict__ wvn,
                                              float* __restrict__ as_out,
                                              float* __restrict__ ad_out,
                                              float* __restrict__ gbuf,
                                              const int* __restrict__ ptr, int N) {
    __shared__ float arr[16][132];
    __shared__ int gids[16];
    int tid = threadIdx.x;
    int g = tid & 15;                    // 8 channels per lane
    int node = tid >> 4;
    int n0 = blockIdx.x * 16;
    int n = n0 + node;
    bool active = n < N;
    int hh = g >> 2;
    int beg = 0, end = 0;
    float ad = 0.f;
    if (active) {
        beg = rp[n]; end = rp[n + 1];
        ad = a_d[(size_t)n * HEADS + hh];
    }
    // pass 1: per-head max, edges split over 4 lanes, unroll 2
    float amax = -1e30f;
    int j = beg + (g & 3);
    for (; j + 4 < end; j += 8) {
        int s0 = col[j], s1 = col[j + 4];
        float a0 = lrelu(a_s[(size_t)s0 * HEADS + hh] + ad);
        float a1 = lrelu(a_s[(size_t)s1 * HEADS + hh] + ad);
        amax = fmaxf(amax, fmaxf(a0, a1));
    }
    for (; j < end; j += 4)
        amax = fmaxf(amax, lrelu(a_s[(size_t)col[j] * HEADS + hh] + ad));
    amax = fmaxf(amax, __shfl_xor(amax, 1));
    amax = fmaxf(amax, __shfl_xor(amax, 2));
    // pass 2: unroll 4 for memory ILP
    float den = 0.f;
    float acc1[8] = {}, acc2[8] = {};
    j = beg;
    for (; j + 3 < end; j += 4) {
        int s0 = col[j], s1 = col[j + 1], s2 = col[j + 2], s3 = col[j + 3];
        float q0 = a_s[(size_t)s0 * HEADS + hh];
        float q1 = a_s[(size_t)s1 * HEADS + hh];
        float q2 = a_s[(size_t)s2 * HEADS + hh];
        float q3 = a_s[(size_t)s3 * HEADS + hh];
        uint4 z0 = *(const uint4*)(zb + (size_t)s0 * DIM + 8 * g);
        uint4 z1 = *(const uint4*)(zb + (size_t)s1 * DIM + 8 * g);
        uint4 z2 = *(const uint4*)(zb + (size_t)s2 * DIM + 8 * g);
        uint4 z3 = *(const uint4*)(zb + (size_t)s3 * DIM + 8 * g);
        float e0 = __expf(lrelu(q0 + ad) - amax);
        float e1 = __expf(lrelu(q1 + ad) - amax);
        float e2 = __expf(lrelu(q2 + ad) - amax);
        float e3 = __expf(lrelu(q3 + ad) - amax);
        den += (e0 + e1) + (e2 + e3);
        accum8(z0, e0, acc1, acc2);
        accum8(z1, e1, acc1, acc2);
        accum8(z2, e2, acc1, acc2);
        accum8(z3, e3, acc1, acc2);
    }
    for (; j < end; j++) {
        int s = col[j];
        float a = lrelu(a_s[(size_t)s * HEADS + hh] + ad);
        float ex = __expf(a - amax);
        den += ex;
        uint4 zv = *(const uint4*)(zb + (size_t)s * DIM + 8 * g);
        accum8(zv, ex, acc1, acc2);
    }
    float out[8];
    if (active) {
        float inv = 1.f / den;
        size_t base = (size_t)n * DIM + 8 * g;
        float4 h0 = *(const float4*)(h + base);
        float4 h1 = *(const float4*)(h + base + 4);
        float hv[8] = {h0.x, h0.y, h0.z, h0.w, h1.x, h1.y, h1.z, h1.w};
        #pragma unroll
        for (int c = 0; c < 8; c++) {
            float o = acc1[c] * inv + acc2[c];
            float e = o > 0.f ? o : (__expf(o) - 1.f);
            out[c] = hv[c] + e;
        }
    } else {
        #pragma unroll
        for (int c = 0; c < 8; c++) out[c] = 0.f;
    }

    if (!gbuf) {
        if (active) {
            size_t base = (size_t)n * DIM + 8 * g;
            *(float4*)(h + base) = make_float4(out[0], out[1], out[2], out[3]);
            *(float4*)(h + base + 4) = make_float4(out[4], out[5], out[6], out[7]);
            if (wvn) {   // fused next-layer attention logits (exact fp32)
                float p[8] = {};
                int c0 = 8 * g;
                #pragma unroll
                for (int c = 0; c < 8; c++) {
                    const float* w = wvn + (c0 + c) * 8;
                    #pragma unroll
                    for (int jj = 0; jj < 8; jj++) p[jj] += out[c] * w[jj];
                }
                #pragma unroll
                for (int off = 1; off < 16; off <<= 1)
                    #pragma unroll
                    for (int jj = 0; jj < 8; jj++) p[jj] += __shfl_xor(p[jj], off);
                if (g == 0) {
                    #pragma unroll
                    for (int jj = 0; jj < 4; jj++) {
                        as_out[(size_t)n * HEADS + jj] = p[jj];
                        ad_out[(size_t)n * HEADS + jj] = p[4 + jj];
                    }
                }
            }
        }
    } else {
        // fused graph readout: block-local run-length reduction, few atomics
        *(float4*)&arr[node][8 * g] = make_float4(out[0], out[1], out[2], out[3]);
        *(float4*)&arr[node][8 * g + 4] = make_float4(out[4], out[5], out[6], out[7]);
        if (tid < 16) gids[tid] = (n0 + tid < N) ? ptr[n0 + tid] : -1;
        __syncthreads();
        if (tid < 128) {
            int c = tid;
            float acc = 0.f;
            int cur = -1;
            #pragma unroll
            for (int i = 0; i < 16; i++) {
                int gid = gids[i];
                if (gid != cur) {
                    if (cur >= 0) atomicAdd(&gbuf[(size_t)cur * DIM + c], acc);
                    cur = gid;
                    acc = 0.f;
                }
                if (gid >= 0) acc += arr[i][c];
            }
            if (cur >= 0) atomicAdd(&gbuf[(size_t)cur * DIM + c], acc);
        }
    }
}

// ---------------- readout phase 2: mean + relu + MLP ----------------
__global__ __launch_bounds__(128) void k_red2(const float* __restrict__ g,
                                              const int* __restrict__ ptr,
                                              const float* __restrict__ w0,
                                              const float* __restrict__ b0,
                                              const float* __restrict__ w1,
                                              const float* __restrict__ b1,
                                              float* __restrict__ y, int N) {
    __shared__ float gsh[DIM];
    int b = blockIdx.x;
    int tid = threadIdx.x;
    int lo = 0, hi = N;
    while (lo < hi) { int m = (lo + hi) >> 1; if (ptr[m] < b) lo = m + 1; else hi = m; }
    int start = lo;
    hi = N;
    while (lo < hi) { int m = (lo + hi) >> 1; if (ptr[m] < b + 1) lo = m + 1; else hi = m; }
    int end = lo;
    float cnt = (float)(end - start);
    float gv = g[(size_t)b * DIM + tid] / fmaxf(cnt, 1.f);
    gsh[tid] = fmaxf(gv, 0.f);
    __syncthreads();
    if (tid < 64) {
        float hj = b0[tid];
        for (int k = 0; k < DIM; k++) hj += gsh[k] * w0[k * 64 + tid];
        hj = fmaxf(hj, 0.f);
        float p = hj * w1[tid];
        #pragma unroll
        for (int off = 32; off > 0; off >>= 1) p += __shfl_down(p, off);
        if (tid == 0) y[b] = p + b1[0];
    }
}

extern "C" void kernel_launch(void* const* d_in, const int* in_sizes, int n_in,
                              void* d_out, int out_size, void* d_ws, size_t ws_size,
                              hipStream_t stream) {
    const int* ei = (const int*)d_in[1];
    const int* ptr = (const int*)d_in[2];
    const float* emb = (const float*)d_in[3];
    const float* lin_w = (const float*)d_in[4];
    const float* att_s = (const float*)d_in[5];
    const float* att_d = (const float*)d_in[6];
    const float* w0 = (const float*)d_in[7];
    const float* b0 = (const float*)d_in[8];
    const float* w1 = (const float*)d_in[9];
    const float* b1 = (const float*)d_in[10];
    float* y = (float*)d_out;

    const int N = in_sizes[0];       // 50000
    const int E = in_sizes[1] / 2;   // 600000
    const int B = out_size;          // 128

    char* wp = (char*)d_ws;
    auto alloc = [&](size_t bytes) {
        void* p = (void*)wp;
        wp += (bytes + 255) & ~(size_t)255;
        return p;
    };
    float* h = (float*)alloc((size_t)N * DIM * 4);
    u16* zb = (u16*)alloc((size_t)N * DIM * 2);
    float* a_s0 = (float*)alloc((size_t)N * HEADS * 4);
    float* a_d0 = (float*)alloc((size_t)N * HEADS * 4);
    float* a_s1 = (float*)alloc((size_t)N * HEADS * 4);
    float* a_d1 = (float*)alloc((size_t)N * HEADS * 4);
    int* deg = (int*)alloc((size_t)N * 4);
    int* rp = (int*)alloc((size_t)(N + 1) * 4);
    int* cur = (int*)alloc((size_t)N * 4);
    int* col = (int*)alloc((size_t)(E + N) * 4);
    int* part = (int*)alloc(64 * 4);
    int* partoff = (int*)alloc(64 * 4);
    float* z0 = (float*)alloc(DIM * 4);
    u16* WTh = (u16*)alloc((size_t)2 * DIM * DIM * 2);
    u16* WTl = (u16*)alloc((size_t)2 * DIM * DIM * 2);
    float* wv = (float*)alloc((size_t)2 * DIM * 8 * 4);
    float* gbuf = (float*)alloc((size_t)B * DIM * 4);

    // CSR build
    hipMemsetAsync(deg, 0, (size_t)N * 4, stream);
    hipMemsetAsync(gbuf, 0, (size_t)B * DIM * 4, stream);
    k_count<<<(E + 255) / 256, 256, 0, stream>>>(ei, deg, E);
    int nb = (N + 1023) / 1024;
    k_scan_block<<<nb, 1024, 0, stream>>>(deg, rp, part, N);
    k_scan_part<<<1, 64, 0, stream>>>(part, partoff, nb);
    k_scan_add<<<(N + 255) / 256, 256, 0, stream>>>(rp, cur, col, deg, partoff, N);
    k_scatter<<<(E + 255) / 256, 256, 0, stream>>>(ei, cur, col, E);

    // weight prep + layer-0 shortcut (fused layer-1 logits)
    k_prep<<<2, 256, 0, stream>>>(lin_w, att_s, att_d, WTh, WTl, wv);
    k_z0<<<1, DIM, 0, stream>>>(emb, lin_w, z0);
    k_hinit<<<(N + 15) / 16, 256, 0, stream>>>(emb, z0, rp, wv, h, a_s0, a_d0, N);

    int gblocks = (N + GM - 1) / GM;
    int ablocks = (N + 15) / 16;
    // GAT layer 1
    k_gemm<<<gblocks, 256, 0, stream>>>(h, WTh, WTl, zb, N);
    k_aggr<<<ablocks, 256, 0, stream>>>(zb, a_s0, a_d0, rp, col, h,
                                        wv + (size_t)DIM * 8, a_s1, a_d1,
                                        nullptr, nullptr, N);
    // GAT layer 2 (fused readout, no h write)
    k_gemm<<<gblocks, 256, 0, stream>>>(h, WTh + (size_t)DIM * DIM,
                                        WTl + (size_t)DIM * DIM, zb, N);
    k_aggr<<<ablocks, 256, 0, stream>>>(zb, a_s1, a_d1, rp, col, h,
                                        nullptr, nullptr, nullptr,
                                        gbuf, ptr, N);

    // MLP readout
    k_red2<<<B, 128, 0, stream>>>(gbuf, ptr, w0, b0, w1, b1, y, N);
}